// Round 5
// baseline (245.559 us; speedup 1.0000x reference)
//
#include <hip/hip_runtime.h>
#include <hip/hip_bf16.h>
#include <math.h>

#define HH 512
#define WW 512
#define BB 8
#define TT 5
#define MID 16
#define HWSZ (HH*WW)      /* 262144 = 2^18 */
#define NPIX (BB*HWSZ)    /* 2097152 */

typedef __attribute__((ext_vector_type(8))) short bf16x8;
typedef __attribute__((ext_vector_type(4))) short bf16x4;
typedef __attribute__((ext_vector_type(4))) float f32x4;

#if __has_builtin(__builtin_amdgcn_exp2f)
#define EXP2F(x) __builtin_amdgcn_exp2f(x)
#else
#define EXP2F(x) exp2f(x)
#endif

#define LOG2E 1.4426950408889634f

// ---------- bf16 helpers ----------
__device__ inline unsigned short f2bf(float f){          // RNE (used in prep only)
  unsigned u = __float_as_uint(f);
  u = u + 0x7fffu + ((u >> 16) & 1u);
  return (unsigned short)(u >> 16);
}
// fast round-half-up pack of two floats -> bf16 pair (low16 = a, high16 = b)
__device__ inline unsigned packpair(float a, float b){
  unsigned ua = __float_as_uint(a) + 0x8000u;
  unsigned ub = __float_as_uint(b) + 0x8000u;
  return __builtin_amdgcn_perm(ub, ua, 0x07060302u);
}
__device__ inline float blo(unsigned u){ return __uint_as_float(u << 16); }
__device__ inline float bhi(unsigned u){ return __uint_as_float(u & 0xffff0000u); }

union U4B { uint4 u; bf16x8 h; };
union U2B { uint2 u; bf16x4 h; };

// ---------- consts layout (floats, in cst) ----------
// [162..177] bi1 (BN1 bias; BN1 scale folded into wsA1 weights)
// [242] bias*log2e
// [288..303] sc2a  [304..319] bi2a
// [320..335] sc3a  [336..351] bi3a

// ================= kernel 1: |raw_diff| accumulate + partial stats; block 2048 = weight prep =================
__global__ __launch_bounds__(256) void k_acc(const float* __restrict__ rd,
    float4* __restrict__ acc, float2* __restrict__ partial,
    const float* __restrict__ w1, const float* __restrict__ g1, const float* __restrict__ b1,
    const float* __restrict__ rm1, const float* __restrict__ rv1,
    const float* __restrict__ w2, const float* __restrict__ g2, const float* __restrict__ b2,
    const float* __restrict__ rm2, const float* __restrict__ rv2,
    const float* __restrict__ w3, const float* __restrict__ g3, const float* __restrict__ b3,
    const float* __restrict__ rm3, const float* __restrict__ rv3,
    const float* __restrict__ w4, const float* __restrict__ bias0,
    float* __restrict__ cst, uint2* __restrict__ wsA1,
    unsigned* __restrict__ wsB2, unsigned* __restrict__ wsB3, uint2* __restrict__ wsB4){
  int t = threadIdx.x;
  if (blockIdx.x == 2048){
    // ---- weight prep ----
    if (t == 0) cst[242] = bias0[0] * LOG2E;
    if (t < 16){
      float s1 = g1[t] * rsqrtf(rv1[t] + 1e-5f);
      cst[162 + t] = b1[t] - rm1[t] * s1;
      float c2 = g2[t] * rsqrtf(rv2[t] + 1e-5f);
      cst[288 + t] = c2; cst[304 + t] = b2[t] - rm2[t] * c2;
      float c3 = g3[t] * rsqrtf(rv3[t] + 1e-5f);
      cst[320 + t] = c3; cst[336 + t] = b3[t] - rm3[t] * c3;
    }
    // A-frag for conv1 16x16x16 MFMA: lane holds w1sc[o=lane&15][tap=(lane>>4)*4+j],
    // taps >= 9 ZERO; BN1 scale folded in.
    if (t < 64){
      int o = t & 15, qq = t >> 4;
      float s1o = g1[o] * rsqrtf(rv1[o] + 1e-5f);
      unsigned pk2[2];
      #pragma unroll
      for (int h = 0; h < 2; h++){
        unsigned lo = 0, hi = 0;
        int tp0 = qq*4 + 2*h, tp1 = tp0 + 1;
        if (tp0 < 9){ float sw = 0.f; for (int f = 0; f < TT; f++) sw += w1[o*45 + f*9 + tp0]; lo = f2bf(sw * s1o); }
        if (tp1 < 9){ float sw = 0.f; for (int f = 0; f < TT; f++) sw += w1[o*45 + f*9 + tp1]; hi = f2bf(sw * s1o); }
        pk2[h] = lo | (hi << 16);
      }
      wsA1[t] = make_uint2(pk2[0], pk2[1]);
    }
    // conv2/conv3 weight fragments for 16x16x32 MFMA (A operand); tap 9 ZERO.
    for (int it = 0; it < 5; it++){
      int idx = it * 256 + t;          // 0..1279
      int m = idx >> 8, rem = idx & 255;
      int L = rem >> 2, jj = rem & 3;
      int out = L & 15, q = L >> 4;
      unsigned v2 = 0, v3 = 0;
      #pragma unroll
      for (int h = 0; h < 2; h++){
        int j = 2*jj + h;
        int k = q*8 + j;
        int tap = 2*m + (k >> 4);
        int ci = k & 15;
        unsigned bv2 = 0, bv3 = 0;
        if (tap < 9){
          bv2 = f2bf(w2[out*144 + ci*9 + tap]);
          bv3 = f2bf(w3[out*144 + ci*9 + tap]);
        }
        v2 |= bv2 << (16*h);
        v3 |= bv3 << (16*h);
      }
      wsB2[idx] = v2; wsB3[idx] = v3;
    }
    // A-fragments for w4 16x16x16 MFMA (row = output o, k = channel), *log2e.
    if (t < 192){
      int c = t >> 6, L = t & 63;
      int n = L & 15, q = L >> 4;
      int o = c*16 + n;
      unsigned pk0 = 0, pk1 = 0;
      if (o < 45){
        unsigned b0 = f2bf(w4[o*16 + q*4 + 0] * LOG2E);
        unsigned b1v = f2bf(w4[o*16 + q*4 + 1] * LOG2E);
        unsigned b2v = f2bf(w4[o*16 + q*4 + 2] * LOG2E);
        unsigned b3v = f2bf(w4[o*16 + q*4 + 3] * LOG2E);
        pk0 = b0 | (b1v << 16);
        pk1 = b2v | (b3v << 16);
      }
      wsB4[c*64 + L] = make_uint2(pk0, pk1);
    }
    return;
  }
  // ---- acc path ----
  int gt = blockIdx.x * 256 + t;            // 0..524287
  int i = gt << 2;
  int b = i >> 18, p = i & (HWSZ - 1);
  const float* base = rd + (size_t)b * 4 * HWSZ + p;
  float4 f0 = *(const float4*)(base);
  float4 f1 = *(const float4*)(base + HWSZ);
  float4 f2 = *(const float4*)(base + 2*HWSZ);
  float4 f3 = *(const float4*)(base + 3*HWSZ);
  float4 s4;
  s4.x = fabsf(f0.x) + fabsf(f1.x) + fabsf(f2.x) + fabsf(f3.x);
  s4.y = fabsf(f0.y) + fabsf(f1.y) + fabsf(f2.y) + fabsf(f3.y);
  s4.z = fabsf(f0.z) + fabsf(f1.z) + fabsf(f2.z) + fabsf(f3.z);
  s4.w = fabsf(f0.w) + fabsf(f1.w) + fabsf(f2.w) + fabsf(f3.w);
  acc[gt] = s4;
  float s  = s4.x + s4.y + s4.z + s4.w;
  float s2 = s4.x*s4.x + s4.y*s4.y + s4.z*s4.z + s4.w*s4.w;
  #pragma unroll
  for (int off = 32; off; off >>= 1){
    s  += __shfl_down(s,  off);
    s2 += __shfl_down(s2, off);
  }
  __shared__ float ls[4], ls2[4];
  int lane = t & 63, wid = t >> 6;
  if (lane == 0){ ls[wid] = s; ls2[wid] = s2; }
  __syncthreads();
  if (t == 0)
    partial[blockIdx.x] = make_float2(ls[0]+ls[1]+ls[2]+ls[3],
                                      ls2[0]+ls2[1]+ls2[2]+ls2[3]);
}

// ======== kernel 2: stats finalize + FUSED conv1 (MFMA) + conv2 (MFMA) ========
#define TR 12
#define TC 68
__global__ __launch_bounds__(256) void k_conv12(const float* __restrict__ acc,
                                                const float2* __restrict__ partial,
                                                const float* __restrict__ C,
                                                const uint2* __restrict__ wsA1,
                                                const unsigned* __restrict__ wsB2,
                                                uint2* __restrict__ h2){
  __shared__ struct {
    float AT[14*72];        // 4032 B  (conv1 garbage taps may read past end -> stays in struct)
    uint4 PLq[816*2];       // 26112 B, pixel-major: pixel p at bytes p*32, chSel half at +16
  } SM;
  __shared__ float rs[4], rs2[4];
  int tid = threadIdx.x;
  int blk = blockIdx.x;                    // 8 xt | 64 yt | 8 b
  int xt = blk & 7, yt = (blk >> 3) & 63, b = blk >> 9;
  int y0 = yt << 3, x0 = xt << 6;

  // ---- phase -1: reduce partial[2048] -> mean, inv (identical in every block) ----
  float s = 0.f, s2 = 0.f;
  for (int j = tid; j < 1024; j += 256){
    float4 v = ((const float4*)partial)[j];
    s += v.x + v.z; s2 += v.y + v.w;
  }
  #pragma unroll
  for (int off = 32; off; off >>= 1){
    s  += __shfl_down(s,  off);
    s2 += __shfl_down(s2, off);
  }
  if ((tid & 63) == 0){ rs[tid >> 6] = s; rs2[tid >> 6] = s2; }
  __syncthreads();
  float S  = rs[0] + rs[1] + rs[2] + rs[3];
  float S2 = rs2[0] + rs2[1] + rs2[2] + rs2[3];
  float n = (float)NPIX;
  float mean = S / n;
  float var  = (S2 - n * mean * mean) / (n - 1.0f);
  float inv  = 1.f / (sqrtf(var) + 1e-6f);

  const float* ab = acc + ((size_t)b << 18);
  // ---- phase 0: stage normalized acc tile (coalesced), halo/pad = 0 ----
  #pragma unroll
  for (int it = 0; it < 4; it++){
    int idx = it*256 + tid;
    if (idx < 14*72){
      int r = (idx * 1821) >> 17;          // idx/72 exact for idx<1008
      int p = idx - r*72;
      int gy = y0 - 3 + r, gx = x0 - 3 + p;
      float v = 0.f;
      if ((unsigned)gy < HH && (unsigned)gx < WW)
        v = (ab[(gy << 9) + gx] - mean) * inv;
      SM.AT[idx] = v;
    }
  }
  __syncthreads();

  int lane = tid & 63, wv = tid >> 6;
  int col = lane & 15, q = lane >> 4;

  // ---- phase 1: conv1 via MFMA (16out x 16px x K=16; taps>=9 have zero weights) ----
  {
    U2B a1; a1.u = wsA1[lane];
    float4 b1v = *(const float4*)&C[162 + q*4];
    f32x4 cinit = {b1v.x, b1v.y, b1v.z, b1v.w};
    int off_[4];
    #pragma unroll
    for (int j = 0; j < 4; j++){
      int tap = q*4 + j;
      int ky = (tap*11) >> 5;              // tap/3 exact for tap<16
      int kx = tap - 3*ky;
      off_[j] = (ky*72 + kx)*4;            // garbage for tap>=9, stays inside SM
    }
    const char* ATb = (const char*)SM.AT;
    char* PLb = (char*)SM.PLq;
    for (int tt = wv; tt < 51; tt += 4){
      int p = tt*16 + col;                 // 0..815
      int r2 = (p * 241) >> 14;            // p/68 exact for p<816
      int p2 = p - r2*TC;
      int bofs = (r2*72 + p2) * 4;
      float m0 = *(const float*)(ATb + bofs + off_[0]);
      float m1 = *(const float*)(ATb + bofs + off_[1]);
      float m2 = *(const float*)(ATb + bofs + off_[2]);
      float m3 = *(const float*)(ATb + bofs + off_[3]);
      U2B bfr;
      bfr.u.x = packpair(m0, m1);
      bfr.u.y = packpair(m2, m3);
      f32x4 z = __builtin_amdgcn_mfma_f32_16x16x16bf16_1k(a1.h, bfr.h, cinit, 0, 0, 0);
      int gy = y0 - 2 + r2, gx = x0 - 2 + p2;
      unsigned pk0 = 0u, pk1 = 0u;
      if (((unsigned)gy < HH) && ((unsigned)gx < WW)){
        pk0 = packpair(fmaxf(0.f, z[0]), fmaxf(0.f, z[1]));
        pk1 = packpair(fmaxf(0.f, z[2]), fmaxf(0.f, z[3]));
      }
      *(uint2*)(PLb + p*32 + q*8) = make_uint2(pk0, pk1);
    }
  }
  __syncthreads();

  // ---- phase 2: conv2 via MFMA, B-operand from LDS (tap-9 zeroed by weights) ----
  int chSel = q & 1;
  bool hiTap = (q >= 2);
  uint4 wfrag[5];
  #pragma unroll
  for (int m = 0; m < 5; m++) wfrag[m] = ((const uint4*)wsB2)[m*64 + lane];
  float4 sc = *(const float4*)&C[288 + q*4];
  float4 bi = *(const float4*)&C[304 + q*4];
  #pragma unroll
  for (int rr = 0; rr < 2; rr++){
    int ly = wv*2 + rr;
    #pragma unroll
    for (int g = 0; g < 4; g++){
      int lx = g << 4;
      f32x4 cc = {0.f, 0.f, 0.f, 0.f};
      #pragma unroll
      for (int m = 0; m < 5; m++){
        const int ta = 2*m, tb = (2*m + 1 > 8) ? 8 : (2*m + 1);  // tap9 -> tap8 addr (weight=0)
        int dy = (hiTap ? tb/3 : ta/3) - 1;
        int dx = (hiTap ? tb%3 : ta%3) - 1;
        int trow = ly + 2 + 2*dy;            // in [0,11]
        int tpx  = lx + 2 + col + 2*dx;      // in [0,67]
        U4B bv; bv.u = SM.PLq[(unsigned)((trow*TC + tpx) << 1) | (unsigned)chSel];
        U4B wb; wb.u = wfrag[m];
        cc = __builtin_amdgcn_mfma_f32_16x16x32_bf16(wb.h, bv.h, cc, 0, 0, 0);
      }
      float v0 = fmaxf(0.f, fmaf(cc[0], sc.x, bi.x));
      float v1 = fmaxf(0.f, fmaf(cc[1], sc.y, bi.y));
      float v2 = fmaxf(0.f, fmaf(cc[2], sc.z, bi.z));
      float v3 = fmaxf(0.f, fmaf(cc[3], sc.w, bi.w));
      int gy = y0 + ly, gx = x0 + lx + col;
      h2[(size_t)((b << 18) | (gy << 9) | gx)*4 + q] =
          make_uint2(packpair(v0, v1), packpair(v2, v3));
    }
  }
}

// ---------- conv3 MFMA core: A = weights, B = pixel patches (global) ----------
template<bool EDGE>
__device__ inline f32x4 convW4(const uint4* __restrict__ hin, const uint4 wfrag[5],
                               int b, int y, int x0, int col, int q, f32x4 cc){
  int chSel = q & 1;
  bool hiTap = (q >= 2);
  #pragma unroll
  for (int m = 0; m < 5; m++){
    const int ta = 2*m, tb = (2*m + 1 > 8) ? 8 : (2*m + 1);
    int dy = (hiTap ? tb/3 : ta/3) - 1;
    int dx = (hiTap ? tb%3 : ta%3) - 1;
    int yy = y + dy * 4;
    int xx = x0 + col + dx * 4;
    U4B a;
    if (EDGE){
      bool valid = ((unsigned)yy < HH) && ((unsigned)xx < WW);
      a.u = make_uint4(0u, 0u, 0u, 0u);
      if (valid) a.u = hin[(((unsigned)((b << 18) | (yy << 9) | xx)) << 1) | (unsigned)chSel];
    } else {
      a.u = hin[(((unsigned)((b << 18) | (yy << 9) | xx)) << 1) | (unsigned)chSel];
    }
    U4B bb; bb.u = wfrag[m];
    cc = __builtin_amdgcn_mfma_f32_16x16x32_bf16(bb.h, a.h, cc, 0, 0, 0);
  }
  return cc;
}

// ---------- shared epilogue: BN/ReLU, w4 MFMA K=16 (no shuffles), exp2-sigmoid,
// kern -> per-wave LDS as one b64 write per (g,c) ----------
__device__ __forceinline__ void stage2_tail(int g, f32x4 cc, float4 sc, float4 bi,
    float cb, const uint2 bw4[3], char* myL, int q, int col){
  float v0 = fmaxf(0.f, fmaf(cc[0], sc.x, bi.x));
  float v1 = fmaxf(0.f, fmaf(cc[1], sc.y, bi.y));
  float v2 = fmaxf(0.f, fmaf(cc[2], sc.z, bi.z));
  float v3 = fmaxf(0.f, fmaf(cc[3], sc.w, bi.w));
  U2B bb;
  bb.u.x = packpair(v0, v1);             // ch q*4+0, q*4+1 of pixel col
  bb.u.y = packpair(v2, v3);             // ch q*4+2, q*4+3
  char* wp = myL + (g*16 + col)*104 + q*8;
  #pragma unroll
  for (int c = 0; c < 3; c++){
    f32x4 aw = {cb, cb, cb, cb};
    U2B af; af.u = bw4[c];
    aw = __builtin_amdgcn_mfma_f32_16x16x16bf16_1k(af.h, bb.h, aw, 0, 0, 0);
    float k0 = fmaf(10.f, __builtin_amdgcn_rcpf(1.f + EXP2F(-aw[0])), 0.1f);
    float k1 = fmaf(10.f, __builtin_amdgcn_rcpf(1.f + EXP2F(-aw[1])), 0.1f);
    float k2 = fmaf(10.f, __builtin_amdgcn_rcpf(1.f + EXP2F(-aw[2])), 0.1f);
    float k3 = fmaf(10.f, __builtin_amdgcn_rcpf(1.f + EXP2F(-aw[3])), 0.1f);
    *(uint2*)(wp + c*32) = make_uint2(packpair(k0, k1), packpair(k2, k3));
  }
}

// ======== kernel 3: conv3 (dil 4, MFMA) + BN/ReLU + w4 MFMA + sigmoid + enhance ========
// FAST path pipeline, PINNED with sched_barrier(0) so the compiler cannot sink
// the prefetch loads (r1/r4 failure: it rematerialized them at use sites):
//   issue ALL 20 taps -> SB0 -> compute g0,g1 -> issue ALL 45 xal -> SB0 ->
//   compute g2,g3 (hides xal HBM latency) -> stage 3 from registers.
// Peak VGPR ~140 (80 taps during g0/g1; 40 taps + 45 xv during g2/g3) < 168 @ (256,3).
__global__ __launch_bounds__(256, 3) void k_conv3m(const uint4* __restrict__ h2,
                                                   const float* __restrict__ C,
                                                   const unsigned* __restrict__ wsB3,
                                                   const uint2* __restrict__ wsB4,
                                                   const float* __restrict__ xal,
                                                   float* __restrict__ out){
  __shared__ uint2 LB[4][832];               // 4 x 6656 B = 26624 B / block
  int lane = threadIdx.x & 63, wv = threadIdx.x >> 6;
  char* myL = (char*)LB[wv];
  int w = blockIdx.x * 4 + wv;
  int base = w << 6;
  int b = base >> 18, rem = base & (HWSZ - 1);
  int y = rem >> 9, wx = rem & 511;
  uint4 wfrag[5];
  #pragma unroll
  for (int m = 0; m < 5; m++) wfrag[m] = ((const uint4*)wsB3)[m*64 + lane];
  uint2 bw4[3];
  #pragma unroll
  for (int c = 0; c < 3; c++) bw4[c] = wsB4[c*64 + lane];
  int col = lane & 15, q = lane >> 4;
  int chSel = q & 1;
  bool hiTap = (q >= 2);
  float4 sc = *(const float4*)&C[320 + q*4];
  float4 bi = *(const float4*)&C[336 + q*4];
  float cb = C[242];                                    // bias*log2e
  int px = wx + lane;

  bool f1 = (y >= 4) && (y < 508) && (wx >= 64) && (wx <= 384);
  if (f1){
    // ---- pinned pipelined fast path ----
    const int dyA[5] = {-1,-1,0,1,1}, dyB[5] = {-1,0,0,1,1};
    const int dxA[5] = {-1,1,0,-1,1}, dxB[5] = {0,-1,1,0,1};
    const char* hb = (const char*)h2
        + ((((size_t)b << 18) + (unsigned)(y << 9)) << 5)
        + ((unsigned)(wx + col) << 5) + (chSel << 4);
    const char* pmt[5];
    #pragma unroll
    for (int m = 0; m < 5; m++){
      int off = hiTap ? (dyB[m]*65536 + dxB[m]*128)
                      : (dyA[m]*65536 + dxA[m]*128);
      pmt[m] = hb + off;
    }
    // issue ALL 20 tap loads; sched_barrier(0) pins them above the compute
    uint4 tap[4][5];
    #pragma unroll
    for (int g = 0; g < 4; g++){
      #pragma unroll
      for (int m = 0; m < 5; m++)
        tap[g][m] = *(const uint4*)(pmt[m] + g*512);
    }
    __builtin_amdgcn_sched_barrier(0);
    // compute g=0,1 (waits only on the 10 oldest loads; g2/g3 taps stay in flight)
    #pragma unroll
    for (int g = 0; g < 2; g++){
      f32x4 cc = {0.f, 0.f, 0.f, 0.f};
      #pragma unroll
      for (int m = 0; m < 5; m++){
        U4B bv; bv.u = tap[g][m];
        U4B wb; wb.u = wfrag[m];
        cc = __builtin_amdgcn_mfma_f32_16x16x32_bf16(wb.h, bv.h, cc, 0, 0, 0);
      }
      stage2_tail(g, cc, sc, bi, cb, bw4, myL, q, col);
    }
    // issue ALL 45 stage-3 loads; pin; their latency hides under g2/g3 compute
    float xv[TT][9];
    {
      const char* p0 = (const char*)xal + (((size_t)(b*TT)) << 20)
                     + (unsigned)(y << 11) + (px << 2);
      #pragma unroll
      for (int t = 0; t < TT; t++){
        const char* pc = p0 + (size_t)t * (HWSZ*4);
        xv[t][0] = *(const float*)(pc - 2052);
        xv[t][1] = *(const float*)(pc - 2048);
        xv[t][2] = *(const float*)(pc - 2044);
        xv[t][3] = *(const float*)(pc - 4);
        xv[t][4] = *(const float*)(pc);
        xv[t][5] = *(const float*)(pc + 4);
        xv[t][6] = *(const float*)(pc + 2044);
        xv[t][7] = *(const float*)(pc + 2048);
        xv[t][8] = *(const float*)(pc + 2052);
      }
    }
    __builtin_amdgcn_sched_barrier(0);
    // compute g=2,3
    #pragma unroll
    for (int g = 2; g < 4; g++){
      f32x4 cc = {0.f, 0.f, 0.f, 0.f};
      #pragma unroll
      for (int m = 0; m < 5; m++){
        U4B bv; bv.u = tap[g][m];
        U4B wb; wb.u = wfrag[m];
        cc = __builtin_amdgcn_mfma_f32_16x16x32_bf16(wb.h, bv.h, cc, 0, 0, 0);
      }
      stage2_tail(g, cc, sc, bi, cb, bw4, myL, q, col);
    }
    // ---- stage 3 on pre-loaded registers ----
    unsigned kvf[24];
    {
      const uint2* kp = (const uint2*)(myL + lane*104);
      #pragma unroll
      for (int jj = 0; jj < 12; jj++){
        uint2 u = kp[jj];
        kvf[2*jj] = u.x; kvf[2*jj+1] = u.y;
      }
    }
    #pragma unroll
    for (int t = 0; t < TT; t++){
      float ov = 0.f;
      #pragma unroll
      for (int k = 0; k < 9; k++){
        int n = t*9 + k;
        unsigned u = kvf[n >> 1];
        float kf = (n & 1) ? bhi(u) : blo(u);
        ov = fmaf(kf, xv[t][k], ov);
      }
      out[((size_t)(b*TT + t) << 18) + (y << 9) + px] = ov;
    }
  } else {
    // ---- edge path: stages 1+2 as before ----
    bool yIn = (y >= 4) && (y < 508);
    #pragma unroll
    for (int g = 0; g < 4; g++){
      int x0 = wx + g*16;
      f32x4 cc = {0.f, 0.f, 0.f, 0.f};
      bool fast = yIn && (x0 >= 4) && (x0 <= 492);      // wave-uniform branch
      if (fast) cc = convW4<false>(h2, wfrag, b, y, x0, col, q, cc);
      else      cc = convW4<true >(h2, wfrag, b, y, x0, col, q, cc);
      stage2_tail(g, cc, sc, bi, cb, bw4, myL, q, col);
    }
    // ---- stage 3 ----
    unsigned kvf[24];
    {
      const uint2* kp = (const uint2*)(myL + lane*104);
      #pragma unroll
      for (int jj = 0; jj < 12; jj++){
        uint2 u = kp[jj];
        kvf[2*jj] = u.x; kvf[2*jj+1] = u.y;
      }
    }
    bool f3 = (y > 0) && (y < 511) && (wx != 0) && (wx != 448);
    if (f3){
      const char* p0 = (const char*)xal + (((size_t)(b*TT)) << 20)
                     + (unsigned)(y << 11) + (px << 2);
      #pragma unroll
      for (int t = 0; t < TT; t++){
        const char* pc = p0 + (size_t)t * (HWSZ*4);
        float xv[9];
        xv[0] = *(const float*)(pc - 2052);
        xv[1] = *(const float*)(pc - 2048);
        xv[2] = *(const float*)(pc - 2044);
        xv[3] = *(const float*)(pc - 4);
        xv[4] = *(const float*)(pc);
        xv[5] = *(const float*)(pc + 4);
        xv[6] = *(const float*)(pc + 2044);
        xv[7] = *(const float*)(pc + 2048);
        xv[8] = *(const float*)(pc + 2052);
        float ov = 0.f;
        #pragma unroll
        for (int k = 0; k < 9; k++){
          int n = t*9 + k;
          unsigned u = kvf[n >> 1];
          float kf = (n & 1) ? bhi(u) : blo(u);
          ov = fmaf(kf, xv[k], ov);
        }
        out[((size_t)(b*TT + t) << 18) + (y << 9) + px] = ov;
      }
    } else {
      bool mxl = (px > 0), mxr = (px < 511), mym = (y > 0), myp = (y < 511);
      bool msk[9] = { mym&&mxl, mym, mym&&mxr,
                      mxl,      true, mxr,
                      myp&&mxl, myp, myp&&mxr };
      int rowm = mym ? -2048 : 0;
      int rowp = myp ?  2048 : 0;
      int loff = mxl ? -4 : 0;
      int roff = mxr ?  4 : 0;
      const char* base0 = (const char*)(xal + ((size_t)(b*TT) << 18) + (y << 9) + px);
      #pragma unroll
      for (int t = 0; t < TT; t++){
        const char* pc = base0 + (size_t)t * (HWSZ*4);
        const char* pm = pc + rowm;
        const char* pp = pc + rowp;
        float xv[9];
        xv[0] = *(const float*)(pm + loff);
        xv[1] = *(const float*)(pm);
        xv[2] = *(const float*)(pm + roff);
        xv[3] = *(const float*)(pc + loff);
        xv[4] = *(const float*)(pc);
        xv[5] = *(const float*)(pc + roff);
        xv[6] = *(const float*)(pp + loff);
        xv[7] = *(const float*)(pp);
        xv[8] = *(const float*)(pp + roff);
        float ov = 0.f;
        #pragma unroll
        for (int k = 0; k < 9; k++){
          int n = t*9 + k;
          unsigned u = kvf[n >> 1];
          float kf = (n & 1) ? bhi(u) : blo(u);
          float kern = msk[k] ? kf : 0.f;
          ov = fmaf(kern, xv[k], ov);
        }
        out[((size_t)(b*TT + t) << 18) + (y << 9) + px] = ov;
      }
    }
  }
}

extern "C" void kernel_launch(void* const* d_in, const int* in_sizes, int n_in,
                              void* d_out, int out_size, void* d_ws, size_t ws_size,
                              hipStream_t stream){
  const float* xal = (const float*)d_in[0];
  const float* rd  = (const float*)d_in[1];
  const float* w1  = (const float*)d_in[2];
  const float* g1  = (const float*)d_in[3];
  const float* b1  = (const float*)d_in[4];
  const float* rm1 = (const float*)d_in[5];
  const float* rv1 = (const float*)d_in[6];
  const float* w2  = (const float*)d_in[7];
  const float* g2  = (const float*)d_in[8];
  const float* b2  = (const float*)d_in[9];
  const float* rm2 = (const float*)d_in[10];
  const float* rv2 = (const float*)d_in[11];
  const float* w3  = (const float*)d_in[12];
  const float* g3  = (const float*)d_in[13];
  const float* b3  = (const float*)d_in[14];
  const float* rm3 = (const float*)d_in[15];
  const float* rv3 = (const float*)d_in[16];
  const float* w4  = (const float*)d_in[17];
  const float* bias= (const float*)d_in[18];
  float* out = (float*)d_out;

  char* ws = (char*)d_ws;
  float2*   partial = (float2*)ws;                    // 16 KB
  float*    cst   = (float*)(ws + 16384);             // 352 floats used
  unsigned* wsB2  = (unsigned*)(ws + 32768);          // 5 KB
  unsigned* wsB3  = (unsigned*)(ws + 40960);          // 5 KB
  uint2*    wsB4  = (uint2*)(ws + 49152);             // 1.5 KB
  uint2*    wsA1  = (uint2*)(ws + 57344);             // 512 B
  float*    acc   = (float*)(ws + 65536);             // 8 MB
  char*     h2    = (char*)(ws + 65536 + (size_t)NPIX*4);                     // 64 MB

  k_acc<<<2049, 256, 0, stream>>>(rd, (float4*)acc, partial,
                                  w1, g1, b1, rm1, rv1,
                                  w2, g2, b2, rm2, rv2,
                                  w3, g3, b3, rm3, rv3,
                                  w4, bias, cst, wsA1, wsB2, wsB3, wsB4);
  k_conv12<<<4096, 256, 0, stream>>>(acc, partial, cst, wsA1, wsB2, (uint2*)h2);
  k_conv3m<<<NPIX/256, 256, 0, stream>>>((const uint4*)h2, cst, wsB3, wsB4, xal, out);
}

// Round 7
// 239.066 us; speedup vs baseline: 1.0272x; 1.0272x over previous
//
#include <hip/hip_runtime.h>
#include <hip/hip_bf16.h>
#include <math.h>

#define HH 512
#define WW 512
#define BB 8
#define TT 5
#define MID 16
#define HWSZ (HH*WW)      /* 262144 = 2^18 */
#define NPIX (BB*HWSZ)    /* 2097152 */

typedef __attribute__((ext_vector_type(8))) short bf16x8;
typedef __attribute__((ext_vector_type(4))) short bf16x4;
typedef __attribute__((ext_vector_type(4))) float f32x4;

#if __has_builtin(__builtin_amdgcn_exp2f)
#define EXP2F(x) __builtin_amdgcn_exp2f(x)
#else
#define EXP2F(x) exp2f(x)
#endif

#define LOG2E 1.4426950408889634f

// ---------- bf16 helpers ----------
__device__ inline unsigned short f2bf(float f){          // RNE (used in prep only)
  unsigned u = __float_as_uint(f);
  u = u + 0x7fffu + ((u >> 16) & 1u);
  return (unsigned short)(u >> 16);
}
// fast round-half-up pack of two floats -> bf16 pair (low16 = a, high16 = b)
__device__ inline unsigned packpair(float a, float b){
  unsigned ua = __float_as_uint(a) + 0x8000u;
  unsigned ub = __float_as_uint(b) + 0x8000u;
  return __builtin_amdgcn_perm(ub, ua, 0x07060302u);
}
__device__ inline float blo(unsigned u){ return __uint_as_float(u << 16); }
__device__ inline float bhi(unsigned u){ return __uint_as_float(u & 0xffff0000u); }

union U4B { uint4 u; bf16x8 h; };
union U2B { uint2 u; bf16x4 h; };

// ---------- consts layout (floats, in cst) ----------
// [162..177] bi1 (BN1 bias; BN1 scale folded into wsA1 weights)
// [242] bias*log2e
// [288..303] sc2a  [304..319] bi2a
// [320..335] sc3a  [336..351] bi3a

// ================= kernel 1: |raw_diff| accumulate + partial stats; block 2048 = weight prep =================
__global__ __launch_bounds__(256) void k_acc(const float* __restrict__ rd,
    float4* __restrict__ acc, float2* __restrict__ partial,
    const float* __restrict__ w1, const float* __restrict__ g1, const float* __restrict__ b1,
    const float* __restrict__ rm1, const float* __restrict__ rv1,
    const float* __restrict__ w2, const float* __restrict__ g2, const float* __restrict__ b2,
    const float* __restrict__ rm2, const float* __restrict__ rv2,
    const float* __restrict__ w3, const float* __restrict__ g3, const float* __restrict__ b3,
    const float* __restrict__ rm3, const float* __restrict__ rv3,
    const float* __restrict__ w4, const float* __restrict__ bias0,
    float* __restrict__ cst, uint2* __restrict__ wsA1,
    unsigned* __restrict__ wsB2, unsigned* __restrict__ wsB3, uint2* __restrict__ wsB4){
  int t = threadIdx.x;
  if (blockIdx.x == 2048){
    // ---- weight prep ----
    if (t == 0) cst[242] = bias0[0] * LOG2E;
    if (t < 16){
      float s1 = g1[t] * rsqrtf(rv1[t] + 1e-5f);
      cst[162 + t] = b1[t] - rm1[t] * s1;
      float c2 = g2[t] * rsqrtf(rv2[t] + 1e-5f);
      cst[288 + t] = c2; cst[304 + t] = b2[t] - rm2[t] * c2;
      float c3 = g3[t] * rsqrtf(rv3[t] + 1e-5f);
      cst[320 + t] = c3; cst[336 + t] = b3[t] - rm3[t] * c3;
    }
    // A-frag for conv1 16x16x16 MFMA: lane holds w1sc[o=lane&15][tap=(lane>>4)*4+j],
    // taps >= 9 ZERO; BN1 scale folded in.
    if (t < 64){
      int o = t & 15, qq = t >> 4;
      float s1o = g1[o] * rsqrtf(rv1[o] + 1e-5f);
      unsigned pk2[2];
      #pragma unroll
      for (int h = 0; h < 2; h++){
        unsigned lo = 0, hi = 0;
        int tp0 = qq*4 + 2*h, tp1 = tp0 + 1;
        if (tp0 < 9){ float sw = 0.f; for (int f = 0; f < TT; f++) sw += w1[o*45 + f*9 + tp0]; lo = f2bf(sw * s1o); }
        if (tp1 < 9){ float sw = 0.f; for (int f = 0; f < TT; f++) sw += w1[o*45 + f*9 + tp1]; hi = f2bf(sw * s1o); }
        pk2[h] = lo | (hi << 16);
      }
      wsA1[t] = make_uint2(pk2[0], pk2[1]);
    }
    // conv2/conv3 weight fragments for 16x16x32 MFMA (A operand); tap 9 ZERO.
    for (int it = 0; it < 5; it++){
      int idx = it * 256 + t;          // 0..1279
      int m = idx >> 8, rem = idx & 255;
      int L = rem >> 2, jj = rem & 3;
      int out = L & 15, q = L >> 4;
      unsigned v2 = 0, v3 = 0;
      #pragma unroll
      for (int h = 0; h < 2; h++){
        int j = 2*jj + h;
        int k = q*8 + j;
        int tap = 2*m + (k >> 4);
        int ci = k & 15;
        unsigned bv2 = 0, bv3 = 0;
        if (tap < 9){
          bv2 = f2bf(w2[out*144 + ci*9 + tap]);
          bv3 = f2bf(w3[out*144 + ci*9 + tap]);
        }
        v2 |= bv2 << (16*h);
        v3 |= bv3 << (16*h);
      }
      wsB2[idx] = v2; wsB3[idx] = v3;
    }
    // A-fragments for w4 16x16x16 MFMA (row = output o, k = channel), *log2e.
    if (t < 192){
      int c = t >> 6, L = t & 63;
      int n = L & 15, q = L >> 4;
      int o = c*16 + n;
      unsigned pk0 = 0, pk1 = 0;
      if (o < 45){
        unsigned b0 = f2bf(w4[o*16 + q*4 + 0] * LOG2E);
        unsigned b1v = f2bf(w4[o*16 + q*4 + 1] * LOG2E);
        unsigned b2v = f2bf(w4[o*16 + q*4 + 2] * LOG2E);
        unsigned b3v = f2bf(w4[o*16 + q*4 + 3] * LOG2E);
        pk0 = b0 | (b1v << 16);
        pk1 = b2v | (b3v << 16);
      }
      wsB4[c*64 + L] = make_uint2(pk0, pk1);
    }
    return;
  }
  // ---- acc path ----
  int gt = blockIdx.x * 256 + t;            // 0..524287
  int i = gt << 2;
  int b = i >> 18, p = i & (HWSZ - 1);
  const float* base = rd + (size_t)b * 4 * HWSZ + p;
  float4 f0 = *(const float4*)(base);
  float4 f1 = *(const float4*)(base + HWSZ);
  float4 f2 = *(const float4*)(base + 2*HWSZ);
  float4 f3 = *(const float4*)(base + 3*HWSZ);
  float4 s4;
  s4.x = fabsf(f0.x) + fabsf(f1.x) + fabsf(f2.x) + fabsf(f3.x);
  s4.y = fabsf(f0.y) + fabsf(f1.y) + fabsf(f2.y) + fabsf(f3.y);
  s4.z = fabsf(f0.z) + fabsf(f1.z) + fabsf(f2.z) + fabsf(f3.z);
  s4.w = fabsf(f0.w) + fabsf(f1.w) + fabsf(f2.w) + fabsf(f3.w);
  acc[gt] = s4;
  float s  = s4.x + s4.y + s4.z + s4.w;
  float s2 = s4.x*s4.x + s4.y*s4.y + s4.z*s4.z + s4.w*s4.w;
  #pragma unroll
  for (int off = 32; off; off >>= 1){
    s  += __shfl_down(s,  off);
    s2 += __shfl_down(s2, off);
  }
  __shared__ float ls[4], ls2[4];
  int lane = t & 63, wid = t >> 6;
  if (lane == 0){ ls[wid] = s; ls2[wid] = s2; }
  __syncthreads();
  if (t == 0)
    partial[blockIdx.x] = make_float2(ls[0]+ls[1]+ls[2]+ls[3],
                                      ls2[0]+ls2[1]+ls2[2]+ls2[3]);
}

// ======== kernel 2: stats finalize + FUSED conv1 (MFMA) + conv2 (MFMA) ========
#define TR 12
#define TC 68
__global__ __launch_bounds__(256) void k_conv12(const float* __restrict__ acc,
                                                const float2* __restrict__ partial,
                                                const float* __restrict__ C,
                                                const uint2* __restrict__ wsA1,
                                                const unsigned* __restrict__ wsB2,
                                                uint2* __restrict__ h2){
  __shared__ struct {
    float AT[14*72];        // 4032 B  (conv1 garbage taps may read past end -> stays in struct)
    uint4 PLq[816*2];       // 26112 B, pixel-major: pixel p at bytes p*32, chSel half at +16
  } SM;
  __shared__ float rs[4], rs2[4];
  int tid = threadIdx.x;
  int blk = blockIdx.x;                    // 8 xt | 64 yt | 8 b
  int xt = blk & 7, yt = (blk >> 3) & 63, b = blk >> 9;
  int y0 = yt << 3, x0 = xt << 6;

  // ---- phase -1: reduce partial[2048] -> mean, inv (identical in every block) ----
  float s = 0.f, s2 = 0.f;
  for (int j = tid; j < 1024; j += 256){
    float4 v = ((const float4*)partial)[j];
    s += v.x + v.z; s2 += v.y + v.w;
  }
  #pragma unroll
  for (int off = 32; off; off >>= 1){
    s  += __shfl_down(s,  off);
    s2 += __shfl_down(s2, off);
  }
  if ((tid & 63) == 0){ rs[tid >> 6] = s; rs2[tid >> 6] = s2; }
  __syncthreads();
  float S  = rs[0] + rs[1] + rs[2] + rs[3];
  float S2 = rs2[0] + rs2[1] + rs2[2] + rs2[3];
  float n = (float)NPIX;
  float mean = S / n;
  float var  = (S2 - n * mean * mean) / (n - 1.0f);
  float inv  = 1.f / (sqrtf(var) + 1e-6f);

  const float* ab = acc + ((size_t)b << 18);
  // ---- phase 0: stage normalized acc tile (coalesced), halo/pad = 0 ----
  #pragma unroll
  for (int it = 0; it < 4; it++){
    int idx = it*256 + tid;
    if (idx < 14*72){
      int r = (idx * 1821) >> 17;          // idx/72 exact for idx<1008
      int p = idx - r*72;
      int gy = y0 - 3 + r, gx = x0 - 3 + p;
      float v = 0.f;
      if ((unsigned)gy < HH && (unsigned)gx < WW)
        v = (ab[(gy << 9) + gx] - mean) * inv;
      SM.AT[idx] = v;
    }
  }
  __syncthreads();

  int lane = tid & 63, wv = tid >> 6;
  int col = lane & 15, q = lane >> 4;

  // ---- phase 1: conv1 via MFMA (16out x 16px x K=16; taps>=9 have zero weights) ----
  {
    U2B a1; a1.u = wsA1[lane];
    float4 b1v = *(const float4*)&C[162 + q*4];
    f32x4 cinit = {b1v.x, b1v.y, b1v.z, b1v.w};
    int off_[4];
    #pragma unroll
    for (int j = 0; j < 4; j++){
      int tap = q*4 + j;
      int ky = (tap*11) >> 5;              // tap/3 exact for tap<16
      int kx = tap - 3*ky;
      off_[j] = (ky*72 + kx)*4;            // garbage for tap>=9, stays inside SM
    }
    const char* ATb = (const char*)SM.AT;
    char* PLb = (char*)SM.PLq;
    for (int tt = wv; tt < 51; tt += 4){
      int p = tt*16 + col;                 // 0..815
      int r2 = (p * 241) >> 14;            // p/68 exact for p<816
      int p2 = p - r2*TC;
      int bofs = (r2*72 + p2) * 4;
      float m0 = *(const float*)(ATb + bofs + off_[0]);
      float m1 = *(const float*)(ATb + bofs + off_[1]);
      float m2 = *(const float*)(ATb + bofs + off_[2]);
      float m3 = *(const float*)(ATb + bofs + off_[3]);
      U2B bfr;
      bfr.u.x = packpair(m0, m1);
      bfr.u.y = packpair(m2, m3);
      f32x4 z = __builtin_amdgcn_mfma_f32_16x16x16bf16_1k(a1.h, bfr.h, cinit, 0, 0, 0);
      int gy = y0 - 2 + r2, gx = x0 - 2 + p2;
      unsigned pk0 = 0u, pk1 = 0u;
      if (((unsigned)gy < HH) && ((unsigned)gx < WW)){
        pk0 = packpair(fmaxf(0.f, z[0]), fmaxf(0.f, z[1]));
        pk1 = packpair(fmaxf(0.f, z[2]), fmaxf(0.f, z[3]));
      }
      *(uint2*)(PLb + p*32 + q*8) = make_uint2(pk0, pk1);
    }
  }
  __syncthreads();

  // ---- phase 2: conv2 via MFMA, B-operand from LDS (tap-9 zeroed by weights) ----
  int chSel = q & 1;
  bool hiTap = (q >= 2);
  uint4 wfrag[5];
  #pragma unroll
  for (int m = 0; m < 5; m++) wfrag[m] = ((const uint4*)wsB2)[m*64 + lane];
  float4 sc = *(const float4*)&C[288 + q*4];
  float4 bi = *(const float4*)&C[304 + q*4];
  // store base: gy = y0 + wv*2 (+rr), gx = x0 + col (+g*16); byte = pix*32 + q*8
  char* sb = (char*)h2
      + ((((size_t)b << 18) + (unsigned)((y0 + wv*2) << 9) + (unsigned)(x0 + col)) << 5)
      + q*8;
  #pragma unroll
  for (int rr = 0; rr < 2; rr++){
    int ly = wv*2 + rr;
    char* sbr = sb + rr*16384;
    #pragma unroll
    for (int g = 0; g < 4; g++){
      int lx = g << 4;
      f32x4 cc = {0.f, 0.f, 0.f, 0.f};
      #pragma unroll
      for (int m = 0; m < 5; m++){
        const int ta = 2*m, tb = (2*m + 1 > 8) ? 8 : (2*m + 1);  // tap9 -> tap8 addr (weight=0)
        int dy = (hiTap ? tb/3 : ta/3) - 1;
        int dx = (hiTap ? tb%3 : ta%3) - 1;
        int trow = ly + 2 + 2*dy;            // in [0,11]
        int tpx  = lx + 2 + col + 2*dx;      // in [0,67]
        U4B bv; bv.u = SM.PLq[(unsigned)((trow*TC + tpx) << 1) | (unsigned)chSel];
        U4B wb; wb.u = wfrag[m];
        cc = __builtin_amdgcn_mfma_f32_16x16x32_bf16(wb.h, bv.h, cc, 0, 0, 0);
      }
      float v0 = fmaxf(0.f, fmaf(cc[0], sc.x, bi.x));
      float v1 = fmaxf(0.f, fmaf(cc[1], sc.y, bi.y));
      float v2 = fmaxf(0.f, fmaf(cc[2], sc.z, bi.z));
      float v3 = fmaxf(0.f, fmaf(cc[3], sc.w, bi.w));
      *(uint2*)(sbr + g*512) = make_uint2(packpair(v0, v1), packpair(v2, v3));
    }
  }
}

// ---------- conv3 MFMA core: A = weights, B = pixel patches (global) ----------
template<bool EDGE>
__device__ inline f32x4 convW4(const uint4* __restrict__ hin, const uint4 wfrag[5],
                               int b, int y, int x0, int col, int q, f32x4 cc){
  int chSel = q & 1;
  bool hiTap = (q >= 2);
  #pragma unroll
  for (int m = 0; m < 5; m++){
    const int ta = 2*m, tb = (2*m + 1 > 8) ? 8 : (2*m + 1);
    int dy = (hiTap ? tb/3 : ta/3) - 1;
    int dx = (hiTap ? tb%3 : ta%3) - 1;
    int yy = y + dy * 4;
    int xx = x0 + col + dx * 4;
    U4B a;
    if (EDGE){
      bool valid = ((unsigned)yy < HH) && ((unsigned)xx < WW);
      a.u = make_uint4(0u, 0u, 0u, 0u);
      if (valid) a.u = hin[(((unsigned)((b << 18) | (yy << 9) | xx)) << 1) | (unsigned)chSel];
    } else {
      a.u = hin[(((unsigned)((b << 18) | (yy << 9) | xx)) << 1) | (unsigned)chSel];
    }
    U4B bb; bb.u = wfrag[m];
    cc = __builtin_amdgcn_mfma_f32_16x16x32_bf16(bb.h, a.h, cc, 0, 0, 0);
  }
  return cc;
}

// ---------- shared epilogue: BN/ReLU, w4 MFMA K=16 (no shuffles), exp2-sigmoid,
// kern -> per-wave LDS as one b64 write per (g,c) ----------
__device__ __forceinline__ void stage2_tail(int g, f32x4 cc, float4 sc, float4 bi,
    float cb, const uint2 bw4[3], char* myL, int q, int col){
  float v0 = fmaxf(0.f, fmaf(cc[0], sc.x, bi.x));
  float v1 = fmaxf(0.f, fmaf(cc[1], sc.y, bi.y));
  float v2 = fmaxf(0.f, fmaf(cc[2], sc.z, bi.z));
  float v3 = fmaxf(0.f, fmaf(cc[3], sc.w, bi.w));
  U2B bb;
  bb.u.x = packpair(v0, v1);             // ch q*4+0, q*4+1 of pixel col
  bb.u.y = packpair(v2, v3);             // ch q*4+2, q*4+3
  char* wp = myL + (g*16 + col)*104 + q*8;
  #pragma unroll
  for (int c = 0; c < 3; c++){
    f32x4 aw = {cb, cb, cb, cb};
    U2B af; af.u = bw4[c];
    aw = __builtin_amdgcn_mfma_f32_16x16x16bf16_1k(af.h, bb.h, aw, 0, 0, 0);
    float k0 = fmaf(10.f, __builtin_amdgcn_rcpf(1.f + EXP2F(-aw[0])), 0.1f);
    float k1 = fmaf(10.f, __builtin_amdgcn_rcpf(1.f + EXP2F(-aw[1])), 0.1f);
    float k2 = fmaf(10.f, __builtin_amdgcn_rcpf(1.f + EXP2F(-aw[2])), 0.1f);
    float k3 = fmaf(10.f, __builtin_amdgcn_rcpf(1.f + EXP2F(-aw[3])), 0.1f);
    *(uint2*)(wp + c*32) = make_uint2(packpair(k0, k1), packpair(k2, k3));
  }
}

// ---------- pipelined main path (y interior). XM=false: fully interior (r4 fast
// path, codegen-identical). XM=true: x-edge wave (wx==0 or 448) — same imm-offset
// pipelined loads; OOB tap addresses WRAP into valid workspace memory (h2 placed
// first in ws so the only possible overrun lands in the metadata page / acc) and
// are zeroed by cndmask; stage-3 wrapped loads are masked in the FMA (y interior
// => only left/right column masks needed). ----------
template<bool XM>
__device__ __forceinline__ void conv3m_main(const uint4* __restrict__ h2,
    const float* __restrict__ xal, float* __restrict__ out,
    const uint4 wfrag[5], const uint2 bw4[3], float4 sc, float4 bi, float cb,
    char* myL, int b, int y, int wx, int lane, int col, int q, int chSel, bool hiTap){
  const int dyA[5] = {-1,-1,0,1,1}, dyB[5] = {-1,0,0,1,1};
  const int dxA[5] = {-1,1,0,-1,1}, dxB[5] = {0,-1,1,0,1};
  const char* hb = (const char*)h2
      + ((((size_t)b << 18) + (unsigned)(y << 9)) << 5)
      + ((unsigned)(wx + col) << 5) + (chSel << 4);
  const char* pmt[5];
  int dxm[5];
  #pragma unroll
  for (int m = 0; m < 5; m++){
    int dy = hiTap ? dyB[m] : dyA[m];
    int dx = hiTap ? dxB[m] : dxA[m];
    dxm[m] = dx;
    pmt[m] = hb + (dy*65536 + dx*128);
  }
  // taps g0,g1 (issue first; mask after issuing)
  uint4 tapA[2][5];
  #pragma unroll
  for (int g = 0; g < 2; g++){
    #pragma unroll
    for (int m = 0; m < 5; m++)
      tapA[g][m] = *(const uint4*)(pmt[m] + g*512);
  }
  if (XM){
    #pragma unroll
    for (int g = 0; g < 2; g++){
      #pragma unroll
      for (int m = 0; m < 5; m++){
        int xx = wx + col + g*16 + dxm[m]*4;
        if ((unsigned)xx >= WW) tapA[g][m] = make_uint4(0u,0u,0u,0u);
      }
    }
  }
  // prefetch ALL 45 stage-3 patch values (wrapped reads stay in-buffer; masked later)
  float xv[TT][9];
  {
    const char* p0 = (const char*)xal + (((size_t)(b*TT)) << 20)
                   + (unsigned)(y << 11) + ((wx + lane) << 2);
    #pragma unroll
    for (int t = 0; t < TT; t++){
      const char* pc = p0 + (size_t)t * (HWSZ*4);
      xv[t][0] = *(const float*)(pc - 2052);
      xv[t][1] = *(const float*)(pc - 2048);
      xv[t][2] = *(const float*)(pc - 2044);
      xv[t][3] = *(const float*)(pc - 4);
      xv[t][4] = *(const float*)(pc);
      xv[t][5] = *(const float*)(pc + 4);
      xv[t][6] = *(const float*)(pc + 2044);
      xv[t][7] = *(const float*)(pc + 2048);
      xv[t][8] = *(const float*)(pc + 2052);
    }
  }
  // compute g=0,1
  #pragma unroll
  for (int g = 0; g < 2; g++){
    f32x4 cc = {0.f, 0.f, 0.f, 0.f};
    #pragma unroll
    for (int m = 0; m < 5; m++){
      U4B bv; bv.u = tapA[g][m];
      U4B wb; wb.u = wfrag[m];
      cc = __builtin_amdgcn_mfma_f32_16x16x32_bf16(wb.h, bv.h, cc, 0, 0, 0);
    }
    stage2_tail(g, cc, sc, bi, cb, bw4, myL, q, col);
  }
  // taps g2,g3 (latency hidden under g0/g1 compute)
  uint4 tapB[2][5];
  #pragma unroll
  for (int g = 0; g < 2; g++){
    #pragma unroll
    for (int m = 0; m < 5; m++)
      tapB[g][m] = *(const uint4*)(pmt[m] + (g + 2)*512);
  }
  if (XM){
    #pragma unroll
    for (int g = 0; g < 2; g++){
      #pragma unroll
      for (int m = 0; m < 5; m++){
        int xx = wx + col + (g + 2)*16 + dxm[m]*4;
        if ((unsigned)xx >= WW) tapB[g][m] = make_uint4(0u,0u,0u,0u);
      }
    }
  }
  #pragma unroll
  for (int g = 0; g < 2; g++){
    f32x4 cc = {0.f, 0.f, 0.f, 0.f};
    #pragma unroll
    for (int m = 0; m < 5; m++){
      U4B bv; bv.u = tapB[g][m];
      U4B wb; wb.u = wfrag[m];
      cc = __builtin_amdgcn_mfma_f32_16x16x32_bf16(wb.h, bv.h, cc, 0, 0, 0);
    }
    stage2_tail(g + 2, cc, sc, bi, cb, bw4, myL, q, col);
  }
  // ---- stage 3 on pre-loaded registers ----
  unsigned kvf[24];
  {
    const uint2* kp = (const uint2*)(myL + lane*104);
    #pragma unroll
    for (int jj = 0; jj < 12; jj++){
      uint2 u = kp[jj];
      kvf[2*jj] = u.x; kvf[2*jj+1] = u.y;
    }
  }
  int px = wx + lane;
  bool mxl = (px > 0), mxr = (px < 511);   // used only when XM
  #pragma unroll
  for (int t = 0; t < TT; t++){
    float ov = 0.f;
    #pragma unroll
    for (int k = 0; k < 9; k++){
      int n = t*9 + k;
      unsigned u = kvf[n >> 1];
      float kf = (n & 1) ? bhi(u) : blo(u);
      if (XM){
        if (k % 3 == 0)      kf = mxl ? kf : 0.f;
        else if (k % 3 == 2) kf = mxr ? kf : 0.f;
      }
      ov = fmaf(kf, xv[t][k], ov);
    }
    out[((size_t)(b*TT + t) << 18) + (y << 9) + px] = ov;
  }
}

// ======== kernel 3: conv3 (dil 4, MFMA) + BN/ReLU + w4 MFMA + sigmoid + enhance ========
// y-interior waves (97%) take the pipelined path: conv3m_main<false> for fully
// interior, conv3m_main<true> for the one x-edge wave per block. Only y-edge
// waves (16/512 rows) keep the slow masked path.
__global__ __launch_bounds__(256, 3) void k_conv3m(const uint4* __restrict__ h2,
                                                   const float* __restrict__ C,
                                                   const unsigned* __restrict__ wsB3,
                                                   const uint2* __restrict__ wsB4,
                                                   const float* __restrict__ xal,
                                                   float* __restrict__ out){
  __shared__ uint2 LB[4][832];               // 4 x 6656 B = 26624 B / block
  int lane = threadIdx.x & 63, wv = threadIdx.x >> 6;
  char* myL = (char*)LB[wv];
  int w = blockIdx.x * 4 + wv;
  int base = w << 6;
  int b = base >> 18, rem = base & (HWSZ - 1);
  int y = rem >> 9, wx = rem & 511;
  uint4 wfrag[5];
  #pragma unroll
  for (int m = 0; m < 5; m++) wfrag[m] = ((const uint4*)wsB3)[m*64 + lane];
  uint2 bw4[3];
  #pragma unroll
  for (int c = 0; c < 3; c++) bw4[c] = wsB4[c*64 + lane];
  int col = lane & 15, q = lane >> 4;
  int chSel = q & 1;
  bool hiTap = (q >= 2);
  float4 sc = *(const float4*)&C[320 + q*4];
  float4 bi = *(const float4*)&C[336 + q*4];
  float cb = C[242];                                    // bias*log2e
  int px = wx + lane;

  bool yIn = (y >= 4) && (y < 508);
  if (yIn){
    if ((wx >= 64) && (wx <= 384))
      conv3m_main<false>(h2, xal, out, wfrag, bw4, sc, bi, cb, myL,
                         b, y, wx, lane, col, q, chSel, hiTap);
    else
      conv3m_main<true >(h2, xal, out, wfrag, bw4, sc, bi, cb, myL,
                         b, y, wx, lane, col, q, chSel, hiTap);
  } else {
    // ---- y-edge path: stages 1+2 with full masking ----
    #pragma unroll
    for (int g = 0; g < 4; g++){
      int x0 = wx + g*16;
      f32x4 cc = {0.f, 0.f, 0.f, 0.f};
      cc = convW4<true>(h2, wfrag, b, y, x0, col, q, cc);
      stage2_tail(g, cc, sc, bi, cb, bw4, myL, q, col);
    }
    // ---- stage 3 ----
    unsigned kvf[24];
    {
      const uint2* kp = (const uint2*)(myL + lane*104);
      #pragma unroll
      for (int jj = 0; jj < 12; jj++){
        uint2 u = kp[jj];
        kvf[2*jj] = u.x; kvf[2*jj+1] = u.y;
      }
    }
    bool f3 = (y > 0) && (y < 511) && (wx != 0) && (wx != 448);
    if (f3){
      const char* p0 = (const char*)xal + (((size_t)(b*TT)) << 20)
                     + (unsigned)(y << 11) + (px << 2);
      #pragma unroll
      for (int t = 0; t < TT; t++){
        const char* pc = p0 + (size_t)t * (HWSZ*4);
        float xv[9];
        xv[0] = *(const float*)(pc - 2052);
        xv[1] = *(const float*)(pc - 2048);
        xv[2] = *(const float*)(pc - 2044);
        xv[3] = *(const float*)(pc - 4);
        xv[4] = *(const float*)(pc);
        xv[5] = *(const float*)(pc + 4);
        xv[6] = *(const float*)(pc + 2044);
        xv[7] = *(const float*)(pc + 2048);
        xv[8] = *(const float*)(pc + 2052);
        float ov = 0.f;
        #pragma unroll
        for (int k = 0; k < 9; k++){
          int n = t*9 + k;
          unsigned u = kvf[n >> 1];
          float kf = (n & 1) ? bhi(u) : blo(u);
          ov = fmaf(kf, xv[k], ov);
        }
        out[((size_t)(b*TT + t) << 18) + (y << 9) + px] = ov;
      }
    } else {
      bool mxl = (px > 0), mxr = (px < 511), mym = (y > 0), myp = (y < 511);
      bool msk[9] = { mym&&mxl, mym, mym&&mxr,
                      mxl,      true, mxr,
                      myp&&mxl, myp, myp&&mxr };
      int rowm = mym ? -2048 : 0;
      int rowp = myp ?  2048 : 0;
      int loff = mxl ? -4 : 0;
      int roff = mxr ?  4 : 0;
      const char* base0 = (const char*)(xal + ((size_t)(b*TT) << 18) + (y << 9) + px);
      #pragma unroll
      for (int t = 0; t < TT; t++){
        const char* pc = base0 + (size_t)t * (HWSZ*4);
        const char* pm = pc + rowm;
        const char* pp = pc + rowp;
        float xv[9];
        xv[0] = *(const float*)(pm + loff);
        xv[1] = *(const float*)(pm);
        xv[2] = *(const float*)(pm + roff);
        xv[3] = *(const float*)(pc + loff);
        xv[4] = *(const float*)(pc);
        xv[5] = *(const float*)(pc + roff);
        xv[6] = *(const float*)(pp + loff);
        xv[7] = *(const float*)(pp);
        xv[8] = *(const float*)(pp + roff);
        float ov = 0.f;
        #pragma unroll
        for (int k = 0; k < 9; k++){
          int n = t*9 + k;
          unsigned u = kvf[n >> 1];
          float kf = (n & 1) ? bhi(u) : blo(u);
          float kern = msk[k] ? kf : 0.f;
          ov = fmaf(kern, xv[k], ov);
        }
        out[((size_t)(b*TT + t) << 18) + (y << 9) + px] = ov;
      }
    }
  }
}

extern "C" void kernel_launch(void* const* d_in, const int* in_sizes, int n_in,
                              void* d_out, int out_size, void* d_ws, size_t ws_size,
                              hipStream_t stream){
  const float* xal = (const float*)d_in[0];
  const float* rd  = (const float*)d_in[1];
  const float* w1  = (const float*)d_in[2];
  const float* g1  = (const float*)d_in[3];
  const float* b1  = (const float*)d_in[4];
  const float* rm1 = (const float*)d_in[5];
  const float* rv1 = (const float*)d_in[6];
  const float* w2  = (const float*)d_in[7];
  const float* g2  = (const float*)d_in[8];
  const float* b2  = (const float*)d_in[9];
  const float* rm2 = (const float*)d_in[10];
  const float* rv2 = (const float*)d_in[11];
  const float* w3  = (const float*)d_in[12];
  const float* g3  = (const float*)d_in[13];
  const float* b3  = (const float*)d_in[14];
  const float* rm3 = (const float*)d_in[15];
  const float* rv3 = (const float*)d_in[16];
  const float* w4  = (const float*)d_in[17];
  const float* bias= (const float*)d_in[18];
  float* out = (float*)d_out;

  char* ws = (char*)d_ws;
  float2*   partial = (float2*)ws;                    // 16 KB
  float*    cst   = (float*)(ws + 16384);             // 352 floats used
  unsigned* wsB2  = (unsigned*)(ws + 32768);          // 5 KB
  unsigned* wsB3  = (unsigned*)(ws + 40960);          // 5 KB
  uint2*    wsB4  = (uint2*)(ws + 49152);             // 1.5 KB
  uint2*    wsA1  = (uint2*)(ws + 57344);             // 512 B
  // h2 FIRST (64 MB) so x-edge wrapped tap reads can only overrun into acc;
  // acc (8 MB) after it.
  char*     h2    = (char*)(ws + 65536);
  float*    acc   = (float*)(ws + 65536 + (size_t)NPIX*32);

  k_acc<<<2049, 256, 0, stream>>>(rd, (float4*)acc, partial,
                                  w1, g1, b1, rm1, rv1,
                                  w2, g2, b2, rm2, rv2,
                                  w3, g3, b3, rm3, rv3,
                                  w4, bias, cst, wsA1, wsB2, wsB3, wsB4);
  k_conv12<<<4096, 256, 0, stream>>>(acc, partial, cst, wsA1, wsB2, (uint2*)h2);
  k_conv3m<<<NPIX/256, 256, 0, stream>>>((const uint4*)h2, cst, wsB3, wsB4, xal, out);
}